// Round 5
// baseline (283.450 us; speedup 1.0000x reference)
//
#include <hip/hip_runtime.h>
#include <hip/hip_bf16.h>
#include <string.h>

typedef __hip_bfloat16 bf16;
typedef __attribute__((ext_vector_type(8))) short short8;
typedef __attribute__((ext_vector_type(4))) short short4v;
typedef __attribute__((ext_vector_type(4))) float f32x4;

__device__ __forceinline__ float b2f(bf16 v) { return __bfloat162float(v); }
__device__ __forceinline__ bf16  f2b(float v) { return __float2bfloat16(v); }
__device__ __forceinline__ float s2f(short s) {
    return __uint_as_float(((unsigned)(unsigned short)s) << 16);
}
__device__ __forceinline__ short f2s(float v) {
    bf16 t = f2b(v); short s; __builtin_memcpy(&s, &t, 2); return s;
}

#define CC 256
#define HWD 16384    // 128*128

// ---------------------------------------------------------------------------
// K0: transpose x (b,256,4096) fp32 -> x_pm (b,4096,256) bf16
// grid 256 = 4 b * 64 pixel-tiles(64 px); LDS tile with +2 pad (bank-safe)
// ---------------------------------------------------------------------------
__global__ __launch_bounds__(256) void k0_xpose(const float* __restrict__ x,
        bf16* __restrict__ xpm)
{
    __shared__ short tile[64][258];
    int b = blockIdx.x >> 6;
    int p0 = (blockIdx.x & 63) << 6;
    int lp = threadIdx.x & 63;     // pixel within tile
    int c0 = threadIdx.x >> 6;     // channel quarter
    const float* xb = x + ((size_t)b << 20);
    for (int k = 0; k < 64; ++k) {
        int c = c0 * 64 + k;
        tile[lp][c] = f2s(xb[((size_t)c << 12) + p0 + lp]);
    }
    __syncthreads();
    int lc = threadIdx.x & 63;     // channel within strip
    int s = threadIdx.x >> 6;      // strip
    short* ob = (short*)xpm + ((size_t)(b * 4096 + p0) << 8) + s * 64 + lc;
    for (int r = 0; r < 64; ++r)
        ob[(size_t)r << 8] = tile[r][s * 64 + lc];
}

// ---------------------------------------------------------------------------
// K1: off = (conv1x1(x, w_off)+b_off) * sigmoid(conv1x1(x, w_ast)+b_ast)
// off layout (b, 32, 4096) fp32
// ---------------------------------------------------------------------------
__global__ __launch_bounds__(256) void k1_off(const float* __restrict__ x,
        const float* __restrict__ w_off, const float* __restrict__ b_off,
        const float* __restrict__ w_ast, const float* __restrict__ b_ast,
        float* __restrict__ off)
{
    __shared__ __align__(16) float sw[256 * 16];
    const int q = blockIdx.x >> 6;
    const int pix = ((blockIdx.x & 63) << 8) + threadIdx.x;
    for (int i = threadIdx.x; i < 256 * 16; i += 256) {
        int c = i >> 4, jj = i & 15;
        int j = (q << 4) + jj;
        int oc = j >> 1, kind = j & 1;
        sw[i] = kind ? w_ast[oc * 256 + c] : w_off[oc * 256 + c];
    }
    __syncthreads();
    const int b = pix >> 12, hw = pix & 4095;
    float acc[16];
#pragma unroll
    for (int m = 0; m < 16; ++m) acc[m] = 0.f;
    const float* xp = x + ((size_t)b * CC << 12) + hw;
    for (int c = 0; c < 256; ++c) {
        float xv = xp[(size_t)c << 12];
        const float4* wrow = reinterpret_cast<const float4*>(&sw[c << 4]);
#pragma unroll
        for (int m4 = 0; m4 < 4; ++m4) {
            float4 wv = wrow[m4];
            acc[m4 * 4 + 0] += xv * wv.x; acc[m4 * 4 + 1] += xv * wv.y;
            acc[m4 * 4 + 2] += xv * wv.z; acc[m4 * 4 + 3] += xv * wv.w;
        }
    }
#pragma unroll
    for (int m = 0; m < 8; ++m) {
        int oc = (q << 3) + m;
        float o = acc[2 * m]     + b_off[oc];
        float a = acc[2 * m + 1] + b_ast[oc];
        float s = 1.f / (1.f + expf(-a));
        off[((size_t)(b * 32 + oc) << 12) + hw] = o * s;
    }
}

// ---------------------------------------------------------------------------
// K2: def_sample -> xup_pm (bf16, pixel-major (b, 16384, 256))
// one WAVE per up-pixel; lane = 4-channel chunk (g = lane>>4)
// tap rows are coalesced 512-B reads from x_pm
// ---------------------------------------------------------------------------
__global__ __launch_bounds__(256) void k2_defsample(const bf16* __restrict__ xpm,
        const float* __restrict__ off, bf16* __restrict__ xup)
{
    int p = blockIdx.x * 4 + (threadIdx.x >> 6);   // wave id = up-pixel
    int lane = threadIdx.x & 63;
    int b = p >> 14, hw = p & 16383;
    int hy = hw >> 7, wx = hw & 127;
    int h = hy >> 1, w = wx >> 1;
    int g = lane >> 4;
    int och = (g << 3) + ((hy & 1) << 2) + ((wx & 1) << 1);
    float ox = off[((size_t)(b * 32 + och)     << 12) + (h << 6) + w];
    float oy = off[((size_t)(b * 32 + och + 1) << 12) + (h << 6) + w];
    float ix = (wx + 0.5f + ox) * 0.5f - 0.5f;
    float iy = (hy + 0.5f + oy) * 0.5f - 0.5f;
    ix = fminf(fmaxf(ix, 0.f), 63.f);
    iy = fminf(fmaxf(iy, 0.f), 63.f);
    float x0f = floorf(ix), y0f = floorf(iy);
    float fx = ix - x0f, fy = iy - y0f;
    int x0 = (int)x0f, y0 = (int)y0f;
    int x1 = min(x0 + 1, 63), y1 = min(y0 + 1, 63);
    float w00 = (1.f - fx) * (1.f - fy), w01 = fx * (1.f - fy);
    float w10 = (1.f - fx) * fy,        w11 = fx * fy;
    const short* xb = (const short*)xpm + ((size_t)b << 20);  // b*4096*256
    int e = lane * 4;                                          // channel chunk
    const short4v* r00 = (const short4v*)(xb + (((size_t)(y0 << 6) + x0) << 8) + e);
    const short4v* r01 = (const short4v*)(xb + (((size_t)(y0 << 6) + x1) << 8) + e);
    const short4v* r10 = (const short4v*)(xb + (((size_t)(y1 << 6) + x0) << 8) + e);
    const short4v* r11 = (const short4v*)(xb + (((size_t)(y1 << 6) + x1) << 8) + e);
    short4v v00 = *r00, v01 = *r01, v10 = *r10, v11 = *r11;
    short4v pk;
#pragma unroll
    for (int j = 0; j < 4; ++j) {
        float v = w00 * s2f(v00[j]) + w01 * s2f(v01[j])
                + w10 * s2f(v10[j]) + w11 * s2f(v11[j]);
        pk[j] = f2s(v);
    }
    *(short4v*)((short*)xup + (((size_t)(b * HWD + hw)) << 8) + e) = pk;
}

// ---------------------------------------------------------------------------
// K3: comp_pm[b][hw][64] = MFMA GEMM: xup_pm (65536x256 bf16) x cw^T (256x64)
// ---------------------------------------------------------------------------
__global__ __launch_bounds__(256) void k3_comp(const bf16* __restrict__ xup,
        const float* __restrict__ cw, const float* __restrict__ cb,
        float* __restrict__ comp)
{
    const int b = blockIdx.x >> 8;
    const int hw0 = (blockIdx.x & 255) << 6;
    const int lane = threadIdx.x & 63;
    const int n = lane & 15, quad = lane >> 4;
    const int ocb = (threadIdx.x >> 6) << 4;

    short8 bfrag[8];
    const float* wrow = cw + (ocb + n) * 256 + quad * 8;
#pragma unroll
    for (int kc = 0; kc < 8; ++kc) {
        float4 lo = *(const float4*)(wrow + kc * 32);
        float4 hi = *(const float4*)(wrow + kc * 32 + 4);
        short8 f;
        f[0] = f2s(lo.x); f[1] = f2s(lo.y); f[2] = f2s(lo.z); f[3] = f2s(lo.w);
        f[4] = f2s(hi.x); f[5] = f2s(hi.y); f[6] = f2s(hi.z); f[7] = f2s(hi.w);
        bfrag[kc] = f;
    }
    float bias = cb[ocb + n];

    const short* abase = (const short*)xup + ((size_t)(b * HWD) << 8);
    float* cbase = comp + ((size_t)(b * HWD) << 6);

#pragma unroll
    for (int mt = 0; mt < 4; mt += 2) {
        f32x4 acc0 = {0.f, 0.f, 0.f, 0.f};
        f32x4 acc1 = {0.f, 0.f, 0.f, 0.f};
        const short8* ar0 = (const short8*)(abase + (((size_t)(hw0 + mt * 16 + n)) << 8) + quad * 8);
        const short8* ar1 = (const short8*)(abase + (((size_t)(hw0 + mt * 16 + 16 + n)) << 8) + quad * 8);
#pragma unroll
        for (int kc = 0; kc < 8; ++kc) {
            short8 a0 = ar0[kc * 4];
            short8 a1 = ar1[kc * 4];
            acc0 = __builtin_amdgcn_mfma_f32_16x16x32_bf16(a0, bfrag[kc], acc0, 0, 0, 0);
            acc1 = __builtin_amdgcn_mfma_f32_16x16x32_bf16(a1, bfrag[kc], acc1, 0, 0, 0);
        }
#pragma unroll
        for (int r = 0; r < 4; ++r) {
            int hwa = hw0 + mt * 16 + quad * 4 + r;
            cbase[((size_t)hwa << 6) + ocb + n] = acc0[r] + bias;
            cbase[((size_t)(hwa + 16) << 6) + ocb + n] = acc1[r] + bias;
        }
    }
}

// ---------------------------------------------------------------------------
// K45: fused k4a + k5 — one comp-row pass per pixel:
//   kern = softmax(conv1x1(comp,64->9)+fb)           -> bf16 [b][hw][16]
//   toff = (conv(comp,64->8)+tb)*sig(conv+tab)       -> fp32 (b,8,16384)
// ---------------------------------------------------------------------------
__global__ __launch_bounds__(256) void k45_kern_toff(const float* __restrict__ comp,
        const float* __restrict__ fw_g, const float* __restrict__ fb,
        const float* __restrict__ tw, const float* __restrict__ tb,
        const float* __restrict__ taw, const float* __restrict__ tab,
        bf16* __restrict__ kern, float* __restrict__ toff)
{
    __shared__ __align__(16) float fw[64 * 12];
    __shared__ __align__(16) float sw[64 * 16];
    for (int i = threadIdx.x; i < 64 * 12; i += 256) {
        int c = i / 12, k = i % 12;
        fw[i] = (k < 9) ? fw_g[k * 64 + c] : 0.f;
    }
    for (int i = threadIdx.x; i < 64 * 16; i += 256) {
        int c = i >> 4, jj = i & 15;
        int oc = jj >> 1, kind = jj & 1;
        sw[i] = kind ? taw[oc * 64 + c] : tw[oc * 64 + c];
    }
    __syncthreads();
    int pix = blockIdx.x * 256 + threadIdx.x;
    int b = pix >> 14, hw = pix & 16383;
    float a[9];
#pragma unroll
    for (int k = 0; k < 9; ++k) a[k] = fb[k];
    float acc[16];
#pragma unroll
    for (int m = 0; m < 16; ++m) acc[m] = 0.f;
    const float4* row = (const float4*)(comp + ((size_t)(b * HWD + hw) << 6));
    for (int c4 = 0; c4 < 16; ++c4) {
        float4 cv = row[c4];
#pragma unroll
        for (int e = 0; e < 4; ++e) {
            int c = c4 * 4 + e;
            float v = (e == 0) ? cv.x : (e == 1) ? cv.y : (e == 2) ? cv.z : cv.w;
            const float4* wr = reinterpret_cast<const float4*>(&fw[c * 12]);
            float4 w0 = wr[0], w1 = wr[1];
            float w8 = fw[c * 12 + 8];
            a[0] += v * w0.x; a[1] += v * w0.y; a[2] += v * w0.z; a[3] += v * w0.w;
            a[4] += v * w1.x; a[5] += v * w1.y; a[6] += v * w1.z; a[7] += v * w1.w;
            a[8] += v * w8;
            const float4* tr = reinterpret_cast<const float4*>(&sw[c << 4]);
#pragma unroll
            for (int m4 = 0; m4 < 4; ++m4) {
                float4 wv = tr[m4];
                acc[m4 * 4 + 0] += v * wv.x; acc[m4 * 4 + 1] += v * wv.y;
                acc[m4 * 4 + 2] += v * wv.z; acc[m4 * 4 + 3] += v * wv.w;
            }
        }
    }
    // softmax -> kern
    float mx = a[0];
#pragma unroll
    for (int k = 1; k < 9; ++k) mx = fmaxf(mx, a[k]);
    float s = 0.f;
#pragma unroll
    for (int k = 0; k < 9; ++k) { a[k] = expf(a[k] - mx); s += a[k]; }
    float inv = 1.f / s;
    short* kr = (short*)kern + ((size_t)(b * HWD + hw) << 4);
    short8 pk;
#pragma unroll
    for (int k = 0; k < 8; ++k) pk[k] = f2s(a[k] * inv);
    *(short8*)kr = pk;
    kr[8] = f2s(a[8] * inv);
    // gated offsets -> toff
#pragma unroll
    for (int oc = 0; oc < 8; ++oc) {
        float o = acc[2 * oc]     + tb[oc];
        float t = acc[2 * oc + 1] + tab[oc];
        toff[((size_t)(b * 8 + oc) << 14) + hw] = o * (1.f / (1.f + expf(-t)));
    }
}

// ---------------------------------------------------------------------------
// K4b: xfilt_pm[b][hw][c] = sum_k kern[b][hw][k] * xup_pm[b][tap_k(hw)][c]
// thread per (b,hw,chunk of 8 channels)
// ---------------------------------------------------------------------------
__global__ __launch_bounds__(256) void k4b_apply(const bf16* __restrict__ xup,
        const bf16* __restrict__ kern, bf16* __restrict__ xfilt)
{
    int t = blockIdx.x * 256 + threadIdx.x;
    int chunk = t & 31;
    int hw = (t >> 5) & 16383;
    int b = t >> 19;
    int h = hw >> 7, w = hw & 127;

    const short* kr = (const short*)kern + ((size_t)(b * HWD + hw) << 4);
    short8 k8 = *(const short8*)kr;
    float wk[9];
#pragma unroll
    for (int k = 0; k < 8; ++k) wk[k] = s2f(k8[k]);
    wk[8] = s2f(kr[8]);

    float ymask[3] = { h > 0 ? 1.f : 0.f, 1.f, h < 127 ? 1.f : 0.f };
    float xmask[3] = { w > 0 ? 1.f : 0.f, 1.f, w < 127 ? 1.f : 0.f };
    int hy[3] = { (max(h - 1, 0)) << 7, h << 7, (min(h + 1, 127)) << 7 };
    int wx[3] = { max(w - 1, 0), w, min(w + 1, 127) };

    const short* xb = (const short*)xup + ((size_t)(b * HWD) << 8) + chunk * 8;
    float sum[8];
#pragma unroll
    for (int j = 0; j < 8; ++j) sum[j] = 0.f;
#pragma unroll
    for (int dy = 0; dy < 3; ++dy) {
#pragma unroll
        for (int dx = 0; dx < 3; ++dx) {
            float wgt = wk[dy * 3 + dx] * ymask[dy] * xmask[dx];
            short8 v = *(const short8*)(xb + ((size_t)(hy[dy] + wx[dx]) << 8));
#pragma unroll
            for (int j = 0; j < 8; ++j) sum[j] += wgt * s2f(v[j]);
        }
    }
    short8 pk;
#pragma unroll
    for (int j = 0; j < 8; ++j) pk[j] = f2s(sum[j]);
    *(short8*)((short*)xfilt + ((size_t)(b * HWD + hw) << 8) + chunk * 8) = pk;
}

// ---------------------------------------------------------------------------
// K6: trim_op -> out (b,256,16384) fp32
// one WAVE per pixel; lane = 4-channel chunk; coalesced 512-B tap rows
// ---------------------------------------------------------------------------
__global__ __launch_bounds__(256) void k6_trim(const bf16* __restrict__ xfilt,
        const float* __restrict__ toff, float* __restrict__ out)
{
    int p = blockIdx.x * 4 + (threadIdx.x >> 6);   // wave id = pixel
    int lane = threadIdx.x & 63;
    int b = p >> 14, hw = p & 16383;
    int h = hw >> 7, w = hw & 127;
    int g = lane >> 4;
    float ox = toff[((size_t)(b * 8 + 2 * g)     << 14) + hw];
    float oy = toff[((size_t)(b * 8 + 2 * g + 1) << 14) + hw];
    float ix = fminf(fmaxf(w + ox, 0.f), 127.f);
    float iy = fminf(fmaxf(h + oy, 0.f), 127.f);
    float x0f = floorf(ix), y0f = floorf(iy);
    float fx = ix - x0f, fy = iy - y0f;
    int x0 = (int)x0f, y0 = (int)y0f;
    int x1 = min(x0 + 1, 127), y1 = min(y0 + 1, 127);
    float w00 = (1.f - fx) * (1.f - fy), w01 = fx * (1.f - fy);
    float w10 = (1.f - fx) * fy,        w11 = fx * fy;
    const short* xb = (const short*)xfilt + ((size_t)(b * HWD) << 8);
    int e = lane * 4;
    short4v v00 = *(const short4v*)(xb + (((size_t)(y0 << 7) + x0) << 8) + e);
    short4v v01 = *(const short4v*)(xb + (((size_t)(y0 << 7) + x1) << 8) + e);
    short4v v10 = *(const short4v*)(xb + (((size_t)(y1 << 7) + x0) << 8) + e);
    short4v v11 = *(const short4v*)(xb + (((size_t)(y1 << 7) + x1) << 8) + e);
    float* ob = out + ((size_t)b * CC << 14) + hw;
#pragma unroll
    for (int j = 0; j < 4; ++j) {
        float v = w00 * s2f(v00[j]) + w01 * s2f(v01[j])
                + w10 * s2f(v10[j]) + w11 * s2f(v11[j]);
        ob[(size_t)(e + j) << 14] = v;
    }
}

extern "C" void kernel_launch(void* const* d_in, const int* in_sizes, int n_in,
                              void* d_out, int out_size, void* d_ws, size_t ws_size,
                              hipStream_t stream)
{
    const float* x       = (const float*)d_in[0];
    const float* w_off   = (const float*)d_in[1];
    const float* b_off   = (const float*)d_in[2];
    const float* w_ast   = (const float*)d_in[3];
    const float* b_ast   = (const float*)d_in[4];
    const float* comp_w  = (const float*)d_in[5];
    const float* comp_b  = (const float*)d_in[6];
    const float* filt_w  = (const float*)d_in[7];
    const float* filt_b  = (const float*)d_in[8];
    const float* trim_w  = (const float*)d_in[9];
    const float* trim_b  = (const float*)d_in[10];
    const float* trim_aw = (const float*)d_in[11];
    const float* trim_ab = (const float*)d_in[12];
    float* out = (float*)d_out;

    char* ws = (char*)d_ws;
    float* off   = (float*)(ws);                 // 2 MiB (dead after k2)
    bf16*  kern  = (bf16*) (ws);                 // 2 MiB, reuses off region
    bf16*  xup   = (bf16*) (ws + (2ull << 20));  // 32 MiB, pixel-major (b,hw,256)
    float* comp  = (float*)(ws + (34ull << 20)); // 16 MiB, pixel-major (b,hw,64)
    bf16*  xpm   = (bf16*) (ws + (34ull << 20)); // 8 MiB, lives in comp region (dead until k3)
    bf16*  xfilt = (bf16*) (ws + (50ull << 20)); // 32 MiB, pixel-major (b,hw,256)
    float* toff  = (float*)(ws + (82ull << 20)); // 2 MiB (total 84 MiB)

    hipLaunchKernelGGL(k0_xpose,    dim3(256),   dim3(256), 0, stream,
                       x, xpm);
    hipLaunchKernelGGL(k1_off,      dim3(256),   dim3(256), 0, stream,
                       x, w_off, b_off, w_ast, b_ast, off);
    hipLaunchKernelGGL(k2_defsample,dim3(16384), dim3(256), 0, stream,
                       xpm, off, xup);
    hipLaunchKernelGGL(k3_comp,     dim3(1024),  dim3(256), 0, stream,
                       xup, comp_w, comp_b, comp);
    hipLaunchKernelGGL(k45_kern_toff, dim3(256), dim3(256), 0, stream,
                       comp, filt_w, filt_b, trim_w, trim_b, trim_aw, trim_ab,
                       kern, toff);
    hipLaunchKernelGGL(k4b_apply,   dim3(8192),  dim3(256), 0, stream,
                       xup, kern, xfilt);
    hipLaunchKernelGGL(k6_trim,     dim3(16384), dim3(256), 0, stream,
                       xfilt, toff, out);
}

// Round 6
// 212.349 us; speedup vs baseline: 1.3348x; 1.3348x over previous
//
#include <hip/hip_runtime.h>
#include <hip/hip_bf16.h>
#include <string.h>

typedef __hip_bfloat16 bf16;
typedef __attribute__((ext_vector_type(8))) short short8;
typedef __attribute__((ext_vector_type(4))) short short4v;
typedef __attribute__((ext_vector_type(4))) float f32x4;

__device__ __forceinline__ float b2f(bf16 v) { return __bfloat162float(v); }
__device__ __forceinline__ bf16  f2b(float v) { return __float2bfloat16(v); }
__device__ __forceinline__ float s2f(short s) {
    return __uint_as_float(((unsigned)(unsigned short)s) << 16);
}
__device__ __forceinline__ short f2s(float v) {
    bf16 t = f2b(v); short s; __builtin_memcpy(&s, &t, 2); return s;
}

#define CC 256
#define HWD 16384    // 128*128

// ---------------------------------------------------------------------------
// K0: transpose x (b,256,4096) fp32 -> x_pm (b,4096,256) bf16
// ---------------------------------------------------------------------------
__global__ __launch_bounds__(256) void k0_xpose(const float* __restrict__ x,
        bf16* __restrict__ xpm)
{
    __shared__ short tile[64][258];
    int b = blockIdx.x >> 6;
    int p0 = (blockIdx.x & 63) << 6;
    int lp = threadIdx.x & 63;     // pixel within tile
    int c0 = threadIdx.x >> 6;     // channel quarter
    const float* xb = x + ((size_t)b << 20);
    for (int k = 0; k < 64; ++k) {
        int c = c0 * 64 + k;
        tile[lp][c] = f2s(xb[((size_t)c << 12) + p0 + lp]);
    }
    __syncthreads();
    int lc = threadIdx.x & 63;     // channel within strip
    int s = threadIdx.x >> 6;      // strip
    short* ob = (short*)xpm + ((size_t)(b * 4096 + p0) << 8) + s * 64 + lc;
    for (int r = 0; r < 64; ++r)
        ob[(size_t)r << 8] = tile[r][s * 64 + lc];
}

// ---------------------------------------------------------------------------
// K1: off = (conv1x1(x, w_off)+b_off) * sigmoid(conv1x1(x, w_ast)+b_ast)
// ---------------------------------------------------------------------------
__global__ __launch_bounds__(256) void k1_off(const float* __restrict__ x,
        const float* __restrict__ w_off, const float* __restrict__ b_off,
        const float* __restrict__ w_ast, const float* __restrict__ b_ast,
        float* __restrict__ off)
{
    __shared__ __align__(16) float sw[256 * 16];
    const int q = blockIdx.x >> 6;
    const int pix = ((blockIdx.x & 63) << 8) + threadIdx.x;
    for (int i = threadIdx.x; i < 256 * 16; i += 256) {
        int c = i >> 4, jj = i & 15;
        int j = (q << 4) + jj;
        int oc = j >> 1, kind = j & 1;
        sw[i] = kind ? w_ast[oc * 256 + c] : w_off[oc * 256 + c];
    }
    __syncthreads();
    const int b = pix >> 12, hw = pix & 4095;
    float acc[16];
#pragma unroll
    for (int m = 0; m < 16; ++m) acc[m] = 0.f;
    const float* xp = x + ((size_t)b * CC << 12) + hw;
    for (int c = 0; c < 256; ++c) {
        float xv = xp[(size_t)c << 12];
        const float4* wrow = reinterpret_cast<const float4*>(&sw[c << 4]);
#pragma unroll
        for (int m4 = 0; m4 < 4; ++m4) {
            float4 wv = wrow[m4];
            acc[m4 * 4 + 0] += xv * wv.x; acc[m4 * 4 + 1] += xv * wv.y;
            acc[m4 * 4 + 2] += xv * wv.z; acc[m4 * 4 + 3] += xv * wv.w;
        }
    }
#pragma unroll
    for (int m = 0; m < 8; ++m) {
        int oc = (q << 3) + m;
        float o = acc[2 * m]     + b_off[oc];
        float a = acc[2 * m + 1] + b_ast[oc];
        float s = 1.f / (1.f + expf(-a));
        off[((size_t)(b * 32 + oc) << 12) + hw] = o * s;
    }
}

// ---------------------------------------------------------------------------
// K2: def_sample -> xup_pm (bf16, pixel-major (b, 16384, 256))
// one WAVE per up-pixel; lane = 4-channel chunk; coalesced 512-B tap rows
// ---------------------------------------------------------------------------
__global__ __launch_bounds__(256) void k2_defsample(const bf16* __restrict__ xpm,
        const float* __restrict__ off, bf16* __restrict__ xup)
{
    int p = blockIdx.x * 4 + (threadIdx.x >> 6);   // wave id = up-pixel
    int lane = threadIdx.x & 63;
    int b = p >> 14, hw = p & 16383;
    int hy = hw >> 7, wx = hw & 127;
    int h = hy >> 1, w = wx >> 1;
    int g = lane >> 4;
    int och = (g << 3) + ((hy & 1) << 2) + ((wx & 1) << 1);
    float ox = off[((size_t)(b * 32 + och)     << 12) + (h << 6) + w];
    float oy = off[((size_t)(b * 32 + och + 1) << 12) + (h << 6) + w];
    float ix = (wx + 0.5f + ox) * 0.5f - 0.5f;
    float iy = (hy + 0.5f + oy) * 0.5f - 0.5f;
    ix = fminf(fmaxf(ix, 0.f), 63.f);
    iy = fminf(fmaxf(iy, 0.f), 63.f);
    float x0f = floorf(ix), y0f = floorf(iy);
    float fx = ix - x0f, fy = iy - y0f;
    int x0 = (int)x0f, y0 = (int)y0f;
    int x1 = min(x0 + 1, 63), y1 = min(y0 + 1, 63);
    float w00 = (1.f - fx) * (1.f - fy), w01 = fx * (1.f - fy);
    float w10 = (1.f - fx) * fy,        w11 = fx * fy;
    const short* xb = (const short*)xpm + ((size_t)b << 20);  // b*4096*256
    int e = lane * 4;                                          // channel chunk
    short4v v00 = *(const short4v*)(xb + (((size_t)(y0 << 6) + x0) << 8) + e);
    short4v v01 = *(const short4v*)(xb + (((size_t)(y0 << 6) + x1) << 8) + e);
    short4v v10 = *(const short4v*)(xb + (((size_t)(y1 << 6) + x0) << 8) + e);
    short4v v11 = *(const short4v*)(xb + (((size_t)(y1 << 6) + x1) << 8) + e);
    short4v pk;
#pragma unroll
    for (int j = 0; j < 4; ++j) {
        float v = w00 * s2f(v00[j]) + w01 * s2f(v01[j])
                + w10 * s2f(v10[j]) + w11 * s2f(v11[j]);
        pk[j] = f2s(v);
    }
    *(short4v*)((short*)xup + (((size_t)(b * HWD + hw)) << 8) + e) = pk;
}

// ---------------------------------------------------------------------------
// K3: comp_pm[b][hw][64] = MFMA GEMM: xup_pm (65536x256 bf16) x cw^T (256x64)
// ---------------------------------------------------------------------------
__global__ __launch_bounds__(256) void k3_comp(const bf16* __restrict__ xup,
        const float* __restrict__ cw, const float* __restrict__ cb,
        float* __restrict__ comp)
{
    const int b = blockIdx.x >> 8;
    const int hw0 = (blockIdx.x & 255) << 6;
    const int lane = threadIdx.x & 63;
    const int n = lane & 15, quad = lane >> 4;
    const int ocb = (threadIdx.x >> 6) << 4;

    short8 bfrag[8];
    const float* wrow = cw + (ocb + n) * 256 + quad * 8;
#pragma unroll
    for (int kc = 0; kc < 8; ++kc) {
        float4 lo = *(const float4*)(wrow + kc * 32);
        float4 hi = *(const float4*)(wrow + kc * 32 + 4);
        short8 f;
        f[0] = f2s(lo.x); f[1] = f2s(lo.y); f[2] = f2s(lo.z); f[3] = f2s(lo.w);
        f[4] = f2s(hi.x); f[5] = f2s(hi.y); f[6] = f2s(hi.z); f[7] = f2s(hi.w);
        bfrag[kc] = f;
    }
    float bias = cb[ocb + n];

    const short* abase = (const short*)xup + ((size_t)(b * HWD) << 8);
    float* cbase = comp + ((size_t)(b * HWD) << 6);

#pragma unroll
    for (int mt = 0; mt < 4; mt += 2) {
        f32x4 acc0 = {0.f, 0.f, 0.f, 0.f};
        f32x4 acc1 = {0.f, 0.f, 0.f, 0.f};
        const short8* ar0 = (const short8*)(abase + (((size_t)(hw0 + mt * 16 + n)) << 8) + quad * 8);
        const short8* ar1 = (const short8*)(abase + (((size_t)(hw0 + mt * 16 + 16 + n)) << 8) + quad * 8);
#pragma unroll
        for (int kc = 0; kc < 8; ++kc) {
            short8 a0 = ar0[kc * 4];
            short8 a1 = ar1[kc * 4];
            acc0 = __builtin_amdgcn_mfma_f32_16x16x32_bf16(a0, bfrag[kc], acc0, 0, 0, 0);
            acc1 = __builtin_amdgcn_mfma_f32_16x16x32_bf16(a1, bfrag[kc], acc1, 0, 0, 0);
        }
#pragma unroll
        for (int r = 0; r < 4; ++r) {
            int hwa = hw0 + mt * 16 + quad * 4 + r;
            cbase[((size_t)hwa << 6) + ocb + n] = acc0[r] + bias;
            cbase[((size_t)(hwa + 16) << 6) + ocb + n] = acc1[r] + bias;
        }
    }
}

// ---------------------------------------------------------------------------
// K45: fused kern-softmax + trim-offsets, one comp-row pass per pixel
// ---------------------------------------------------------------------------
__global__ __launch_bounds__(256) void k45_kern_toff(const float* __restrict__ comp,
        const float* __restrict__ fw_g, const float* __restrict__ fb,
        const float* __restrict__ tw, const float* __restrict__ tb,
        const float* __restrict__ taw, const float* __restrict__ tab,
        bf16* __restrict__ kern, float* __restrict__ toff)
{
    __shared__ __align__(16) float fw[64 * 12];
    __shared__ __align__(16) float sw[64 * 16];
    for (int i = threadIdx.x; i < 64 * 12; i += 256) {
        int c = i / 12, k = i % 12;
        fw[i] = (k < 9) ? fw_g[k * 64 + c] : 0.f;
    }
    for (int i = threadIdx.x; i < 64 * 16; i += 256) {
        int c = i >> 4, jj = i & 15;
        int oc = jj >> 1, kind = jj & 1;
        sw[i] = kind ? taw[oc * 64 + c] : tw[oc * 64 + c];
    }
    __syncthreads();
    int pix = blockIdx.x * 256 + threadIdx.x;
    int b = pix >> 14, hw = pix & 16383;
    float a[9];
#pragma unroll
    for (int k = 0; k < 9; ++k) a[k] = fb[k];
    float acc[16];
#pragma unroll
    for (int m = 0; m < 16; ++m) acc[m] = 0.f;
    const float4* row = (const float4*)(comp + ((size_t)(b * HWD + hw) << 6));
    for (int c4 = 0; c4 < 16; ++c4) {
        float4 cv = row[c4];
#pragma unroll
        for (int e = 0; e < 4; ++e) {
            int c = c4 * 4 + e;
            float v = (e == 0) ? cv.x : (e == 1) ? cv.y : (e == 2) ? cv.z : cv.w;
            const float4* wr = reinterpret_cast<const float4*>(&fw[c * 12]);
            float4 w0 = wr[0], w1 = wr[1];
            float w8 = fw[c * 12 + 8];
            a[0] += v * w0.x; a[1] += v * w0.y; a[2] += v * w0.z; a[3] += v * w0.w;
            a[4] += v * w1.x; a[5] += v * w1.y; a[6] += v * w1.z; a[7] += v * w1.w;
            a[8] += v * w8;
            const float4* tr = reinterpret_cast<const float4*>(&sw[c << 4]);
#pragma unroll
            for (int m4 = 0; m4 < 4; ++m4) {
                float4 wv = tr[m4];
                acc[m4 * 4 + 0] += v * wv.x; acc[m4 * 4 + 1] += v * wv.y;
                acc[m4 * 4 + 2] += v * wv.z; acc[m4 * 4 + 3] += v * wv.w;
            }
        }
    }
    float mx = a[0];
#pragma unroll
    for (int k = 1; k < 9; ++k) mx = fmaxf(mx, a[k]);
    float s = 0.f;
#pragma unroll
    for (int k = 0; k < 9; ++k) { a[k] = expf(a[k] - mx); s += a[k]; }
    float inv = 1.f / s;
    short* kr = (short*)kern + ((size_t)(b * HWD + hw) << 4);
    short8 pk;
#pragma unroll
    for (int k = 0; k < 8; ++k) pk[k] = f2s(a[k] * inv);
    *(short8*)kr = pk;
    kr[8] = f2s(a[8] * inv);
#pragma unroll
    for (int oc = 0; oc < 8; ++oc) {
        float o = acc[2 * oc]     + tb[oc];
        float t = acc[2 * oc + 1] + tab[oc];
        toff[((size_t)(b * 8 + oc) << 14) + hw] = o * (1.f / (1.f + expf(-t)));
    }
}

// ---------------------------------------------------------------------------
// K4b: xfilt_pm[b][hw][c] = sum_k kern[b][hw][k] * xup_pm[b][tap_k(hw)][c]
// ---------------------------------------------------------------------------
__global__ __launch_bounds__(256) void k4b_apply(const bf16* __restrict__ xup,
        const bf16* __restrict__ kern, bf16* __restrict__ xfilt)
{
    int t = blockIdx.x * 256 + threadIdx.x;
    int chunk = t & 31;
    int hw = (t >> 5) & 16383;
    int b = t >> 19;
    int h = hw >> 7, w = hw & 127;

    const short* kr = (const short*)kern + ((size_t)(b * HWD + hw) << 4);
    short8 k8 = *(const short8*)kr;
    float wk[9];
#pragma unroll
    for (int k = 0; k < 8; ++k) wk[k] = s2f(k8[k]);
    wk[8] = s2f(kr[8]);

    float ymask[3] = { h > 0 ? 1.f : 0.f, 1.f, h < 127 ? 1.f : 0.f };
    float xmask[3] = { w > 0 ? 1.f : 0.f, 1.f, w < 127 ? 1.f : 0.f };
    int hy[3] = { (max(h - 1, 0)) << 7, h << 7, (min(h + 1, 127)) << 7 };
    int wx[3] = { max(w - 1, 0), w, min(w + 1, 127) };

    const short* xb = (const short*)xup + ((size_t)(b * HWD) << 8) + chunk * 8;
    float sum[8];
#pragma unroll
    for (int j = 0; j < 8; ++j) sum[j] = 0.f;
#pragma unroll
    for (int dy = 0; dy < 3; ++dy) {
#pragma unroll
        for (int dx = 0; dx < 3; ++dx) {
            float wgt = wk[dy * 3 + dx] * ymask[dy] * xmask[dx];
            short8 v = *(const short8*)(xb + ((size_t)(hy[dy] + wx[dx]) << 8));
#pragma unroll
            for (int j = 0; j < 8; ++j) sum[j] += wgt * s2f(v[j]);
        }
    }
    short8 pk;
#pragma unroll
    for (int j = 0; j < 8; ++j) pk[j] = f2s(sum[j]);
    *(short8*)((short*)xfilt + ((size_t)(b * HWD + hw) << 8) + chunk * 8) = pk;
}

// ---------------------------------------------------------------------------
// K6: trim_op -> out (b,256,16384) fp32
// block = (b, 32 consecutive pixels). Phase 1: wave-per-pixel coalesced
// gather into LDS[px][ch]. Phase 2: transposed coalesced stores.
// ---------------------------------------------------------------------------
__global__ __launch_bounds__(256) void k6_trim(const bf16* __restrict__ xfilt,
        const float* __restrict__ toff, float* __restrict__ out)
{
    __shared__ float sm[32][260];   // +4 pad breaks power-of-2 conflicts
    int b = blockIdx.x >> 9;
    int hw0 = (blockIdx.x & 511) << 5;
    int wave = threadIdx.x >> 6, lane = threadIdx.x & 63;
    int e = lane * 4;               // channel chunk base
    int g = lane >> 4;              // group
    const short* xb = (const short*)xfilt + ((size_t)(b * HWD) << 8);
    const float* tfx = toff + ((size_t)(b * 8 + 2 * g)     << 14);
    const float* tfy = toff + ((size_t)(b * 8 + 2 * g + 1) << 14);

    for (int i = 0; i < 8; ++i) {
        int pp = wave * 8 + i;
        int hw = hw0 + pp;
        int h = hw >> 7, w = hw & 127;
        float ox = tfx[hw], oy = tfy[hw];
        float ix = fminf(fmaxf(w + ox, 0.f), 127.f);
        float iy = fminf(fmaxf(h + oy, 0.f), 127.f);
        float x0f = floorf(ix), y0f = floorf(iy);
        float fx = ix - x0f, fy = iy - y0f;
        int x0 = (int)x0f, y0 = (int)y0f;
        int x1 = min(x0 + 1, 127), y1 = min(y0 + 1, 127);
        float w00 = (1.f - fx) * (1.f - fy), w01 = fx * (1.f - fy);
        float w10 = (1.f - fx) * fy,        w11 = fx * fy;
        short4v v00 = *(const short4v*)(xb + (((size_t)(y0 << 7) + x0) << 8) + e);
        short4v v01 = *(const short4v*)(xb + (((size_t)(y0 << 7) + x1) << 8) + e);
        short4v v10 = *(const short4v*)(xb + (((size_t)(y1 << 7) + x0) << 8) + e);
        short4v v11 = *(const short4v*)(xb + (((size_t)(y1 << 7) + x1) << 8) + e);
#pragma unroll
        for (int j = 0; j < 4; ++j) {
            sm[pp][e + j] = w00 * s2f(v00[j]) + w01 * s2f(v01[j])
                          + w10 * s2f(v10[j]) + w11 * s2f(v11[j]);
        }
    }
    __syncthreads();
    int lp = threadIdx.x & 31;      // pixel within tile
    int c0 = (threadIdx.x >> 5) << 5; // channel base (32 per thread)
    float* ob = out + (((size_t)b << 8) << 14) + hw0 + lp;
#pragma unroll 8
    for (int k = 0; k < 32; ++k) {
        int c = c0 + k;
        ob[(size_t)c << 14] = sm[lp][c];
    }
}

extern "C" void kernel_launch(void* const* d_in, const int* in_sizes, int n_in,
                              void* d_out, int out_size, void* d_ws, size_t ws_size,
                              hipStream_t stream)
{
    const float* x       = (const float*)d_in[0];
    const float* w_off   = (const float*)d_in[1];
    const float* b_off   = (const float*)d_in[2];
    const float* w_ast   = (const float*)d_in[3];
    const float* b_ast   = (const float*)d_in[4];
    const float* comp_w  = (const float*)d_in[5];
    const float* comp_b  = (const float*)d_in[6];
    const float* filt_w  = (const float*)d_in[7];
    const float* filt_b  = (const float*)d_in[8];
    const float* trim_w  = (const float*)d_in[9];
    const float* trim_b  = (const float*)d_in[10];
    const float* trim_aw = (const float*)d_in[11];
    const float* trim_ab = (const float*)d_in[12];
    float* out = (float*)d_out;

    char* ws = (char*)d_ws;
    float* off   = (float*)(ws);                 // 2 MiB (dead after k2)
    bf16*  kern  = (bf16*) (ws);                 // 2 MiB, reuses off region
    bf16*  xup   = (bf16*) (ws + (2ull << 20));  // 32 MiB, pixel-major (b,hw,256)
    float* comp  = (float*)(ws + (34ull << 20)); // 16 MiB, pixel-major (b,hw,64)
    bf16*  xpm   = (bf16*) (ws + (34ull << 20)); // 8 MiB, in comp region (dead until k3)
    bf16*  xfilt = (bf16*) (ws + (50ull << 20)); // 32 MiB, pixel-major (b,hw,256)
    float* toff  = (float*)(ws + (82ull << 20)); // 2 MiB (total 84 MiB)

    hipLaunchKernelGGL(k0_xpose,    dim3(256),   dim3(256), 0, stream,
                       x, xpm);
    hipLaunchKernelGGL(k1_off,      dim3(256),   dim3(256), 0, stream,
                       x, w_off, b_off, w_ast, b_ast, off);
    hipLaunchKernelGGL(k2_defsample,dim3(16384), dim3(256), 0, stream,
                       xpm, off, xup);
    hipLaunchKernelGGL(k3_comp,     dim3(1024),  dim3(256), 0, stream,
                       xup, comp_w, comp_b, comp);
    hipLaunchKernelGGL(k45_kern_toff, dim3(256), dim3(256), 0, stream,
                       comp, filt_w, filt_b, trim_w, trim_b, trim_aw, trim_ab,
                       kern, toff);
    hipLaunchKernelGGL(k4b_apply,   dim3(8192),  dim3(256), 0, stream,
                       xup, kern, xfilt);
    hipLaunchKernelGGL(k6_trim,     dim3(2048),  dim3(256), 0, stream,
                       xfilt, toff, out);
}

// Round 7
// 188.043 us; speedup vs baseline: 1.5074x; 1.1293x over previous
//
#include <hip/hip_runtime.h>
#include <hip/hip_bf16.h>
#include <string.h>

typedef __hip_bfloat16 bf16;
typedef __attribute__((ext_vector_type(8))) short short8;
typedef __attribute__((ext_vector_type(4))) short short4v;
typedef __attribute__((ext_vector_type(4))) float f32x4;

__device__ __forceinline__ float b2f(bf16 v) { return __bfloat162float(v); }
__device__ __forceinline__ bf16  f2b(float v) { return __float2bfloat16(v); }
__device__ __forceinline__ float s2f(short s) {
    return __uint_as_float(((unsigned)(unsigned short)s) << 16);
}
__device__ __forceinline__ short f2s(float v) {
    bf16 t = f2b(v); short s; __builtin_memcpy(&s, &t, 2); return s;
}

#define CC 256
#define HWD 16384    // 128*128

// ---------------------------------------------------------------------------
// K0: transpose x (b,256,4096) fp32 -> x_pm (b,4096,256) bf16
// ---------------------------------------------------------------------------
__global__ __launch_bounds__(256) void k0_xpose(const float* __restrict__ x,
        bf16* __restrict__ xpm)
{
    __shared__ short tile[64][258];
    int b = blockIdx.x >> 6;
    int p0 = (blockIdx.x & 63) << 6;
    int lp = threadIdx.x & 63;     // pixel within tile
    int c0 = threadIdx.x >> 6;     // channel quarter
    const float* xb = x + ((size_t)b << 20);
    for (int k = 0; k < 64; ++k) {
        int c = c0 * 64 + k;
        tile[lp][c] = f2s(xb[((size_t)c << 12) + p0 + lp]);
    }
    __syncthreads();
    int lc = threadIdx.x & 63;     // channel within strip
    int s = threadIdx.x >> 6;      // strip
    short* ob = (short*)xpm + ((size_t)(b * 4096 + p0) << 8) + s * 64 + lc;
    for (int r = 0; r < 64; ++r)
        ob[(size_t)r << 8] = tile[r][s * 64 + lc];
}

// ---------------------------------------------------------------------------
// K1: MFMA GEMM xpm (4096x256 per b) x [w_off|w_ast interleaved]^T (256x64),
// gate via shfl_xor pair -> off_pm (b,4096,32) fp32
// grid 256 = 4 b * 64 tiles(64 px); 4 waves x 16 combined outputs
// ---------------------------------------------------------------------------
__global__ __launch_bounds__(256) void k1_off(const bf16* __restrict__ xpm,
        const float* __restrict__ w_off, const float* __restrict__ b_off,
        const float* __restrict__ w_ast, const float* __restrict__ b_ast,
        float* __restrict__ offpm)
{
    const int b = blockIdx.x >> 6;
    const int p0 = (blockIdx.x & 63) << 6;
    const int lane = threadIdx.x & 63;
    const int n = lane & 15, quad = lane >> 4;
    const int jb = (threadIdx.x >> 6) << 4;
    const int j = jb + n, oc = j >> 1, kind = j & 1;

    short8 bfrag[8];
    const float* wrow = (kind ? w_ast : w_off) + oc * 256 + quad * 8;
#pragma unroll
    for (int kc = 0; kc < 8; ++kc) {
        float4 lo = *(const float4*)(wrow + kc * 32);
        float4 hi = *(const float4*)(wrow + kc * 32 + 4);
        short8 f;
        f[0] = f2s(lo.x); f[1] = f2s(lo.y); f[2] = f2s(lo.z); f[3] = f2s(lo.w);
        f[4] = f2s(hi.x); f[5] = f2s(hi.y); f[6] = f2s(hi.z); f[7] = f2s(hi.w);
        bfrag[kc] = f;
    }
    float bias = kind ? b_ast[oc] : b_off[oc];

    const short* abase = (const short*)xpm + ((size_t)(b * 4096) << 8);
    float* obase = offpm + ((size_t)(b * 4096) << 5);

#pragma unroll
    for (int mt = 0; mt < 4; mt += 2) {
        f32x4 acc0 = {0.f, 0.f, 0.f, 0.f};
        f32x4 acc1 = {0.f, 0.f, 0.f, 0.f};
        const short8* ar0 = (const short8*)(abase + (((size_t)(p0 + mt * 16 + n)) << 8) + quad * 8);
        const short8* ar1 = (const short8*)(abase + (((size_t)(p0 + mt * 16 + 16 + n)) << 8) + quad * 8);
#pragma unroll
        for (int kc = 0; kc < 8; ++kc) {
            short8 a0 = ar0[kc * 4];
            short8 a1 = ar1[kc * 4];
            acc0 = __builtin_amdgcn_mfma_f32_16x16x32_bf16(a0, bfrag[kc], acc0, 0, 0, 0);
            acc1 = __builtin_amdgcn_mfma_f32_16x16x32_bf16(a1, bfrag[kc], acc1, 0, 0, 0);
        }
#pragma unroll
        for (int r = 0; r < 4; ++r) {
            float v0 = acc0[r] + bias;
            float v1 = acc1[r] + bias;
            float p0v = __shfl_xor(v0, 1, 64);
            float p1v = __shfl_xor(v1, 1, 64);
            if (!(n & 1)) {
                int px = p0 + mt * 16 + quad * 4 + r;
                obase[((size_t)px << 5) + oc] = v0 * (1.f / (1.f + expf(-p0v)));
                obase[((size_t)(px + 16) << 5) + oc] = v1 * (1.f / (1.f + expf(-p1v)));
            }
        }
    }
}

// ---------------------------------------------------------------------------
// K2: def_sample -> xup_pm (bf16, pixel-major (b, 16384, 256))
// one WAVE per up-pixel; lane = 4-channel chunk; coalesced 512-B tap rows
// off_pm reads: all 8 values for a wave live in one 128-B row
// ---------------------------------------------------------------------------
__global__ __launch_bounds__(256) void k2_defsample(const bf16* __restrict__ xpm,
        const float* __restrict__ offpm, bf16* __restrict__ xup)
{
    int p = blockIdx.x * 4 + (threadIdx.x >> 6);   // wave id = up-pixel
    int lane = threadIdx.x & 63;
    int b = p >> 14, hw = p & 16383;
    int hy = hw >> 7, wx = hw & 127;
    int h = hy >> 1, w = wx >> 1;
    int g = lane >> 4;
    int och = (g << 3) + ((hy & 1) << 2) + ((wx & 1) << 1);
    const float* orow = offpm + ((size_t)(b * 4096 + (h << 6) + w) << 5);
    float ox = orow[och], oy = orow[och + 1];
    float ix = (wx + 0.5f + ox) * 0.5f - 0.5f;
    float iy = (hy + 0.5f + oy) * 0.5f - 0.5f;
    ix = fminf(fmaxf(ix, 0.f), 63.f);
    iy = fminf(fmaxf(iy, 0.f), 63.f);
    float x0f = floorf(ix), y0f = floorf(iy);
    float fx = ix - x0f, fy = iy - y0f;
    int x0 = (int)x0f, y0 = (int)y0f;
    int x1 = min(x0 + 1, 63), y1 = min(y0 + 1, 63);
    float w00 = (1.f - fx) * (1.f - fy), w01 = fx * (1.f - fy);
    float w10 = (1.f - fx) * fy,        w11 = fx * fy;
    const short* xb = (const short*)xpm + ((size_t)b << 20);  // b*4096*256
    int e = lane * 4;                                          // channel chunk
    short4v v00 = *(const short4v*)(xb + (((size_t)(y0 << 6) + x0) << 8) + e);
    short4v v01 = *(const short4v*)(xb + (((size_t)(y0 << 6) + x1) << 8) + e);
    short4v v10 = *(const short4v*)(xb + (((size_t)(y1 << 6) + x0) << 8) + e);
    short4v v11 = *(const short4v*)(xb + (((size_t)(y1 << 6) + x1) << 8) + e);
    short4v pk;
#pragma unroll
    for (int j = 0; j < 4; ++j) {
        float v = w00 * s2f(v00[j]) + w01 * s2f(v01[j])
                + w10 * s2f(v10[j]) + w11 * s2f(v11[j]);
        pk[j] = f2s(v);
    }
    *(short4v*)((short*)xup + (((size_t)(b * HWD + hw)) << 8) + e) = pk;
}

// ---------------------------------------------------------------------------
// K3 (fused): MFMA comp tile in LDS, then epilogue computes
//   kern = softmax(conv1x1(comp,64->9)+fb)   -> bf16 [b][hw][16]
//   toff = (conv+tb)*sigmoid(conv+tab)       -> fp32 (b,8,16384)
// grid 1024 = 4 b * 256 tiles(64 px); wave q: q0=kern, q1..3=toff oc split
// ---------------------------------------------------------------------------
__global__ __launch_bounds__(256) void k3_fused(const bf16* __restrict__ xup,
        const float* __restrict__ cw, const float* __restrict__ cb,
        const float* __restrict__ fw_g, const float* __restrict__ fb,
        const float* __restrict__ tw, const float* __restrict__ tb,
        const float* __restrict__ taw, const float* __restrict__ tab,
        bf16* __restrict__ kern, float* __restrict__ toff)
{
    __shared__ float smc[64][65];           // comp tile, +1 pad (2-way max)
    __shared__ __align__(16) float fwS[64 * 12];
    __shared__ __align__(16) float swS[64 * 16];
    for (int i = threadIdx.x; i < 64 * 12; i += 256) {
        int c = i / 12, k = i % 12;
        fwS[i] = (k < 9) ? fw_g[k * 64 + c] : 0.f;
    }
    for (int i = threadIdx.x; i < 64 * 16; i += 256) {
        int c = i >> 4, jj = i & 15;
        int oc = jj >> 1, kind = jj & 1;
        swS[i] = kind ? taw[oc * 64 + c] : tw[oc * 64 + c];
    }

    const int b = blockIdx.x >> 8;
    const int hw0 = (blockIdx.x & 255) << 6;
    const int lane = threadIdx.x & 63;
    const int n = lane & 15, quad = lane >> 4;
    const int ocb = (threadIdx.x >> 6) << 4;

    short8 bfrag[8];
    const float* wrow = cw + (ocb + n) * 256 + quad * 8;
#pragma unroll
    for (int kc = 0; kc < 8; ++kc) {
        float4 lo = *(const float4*)(wrow + kc * 32);
        float4 hi = *(const float4*)(wrow + kc * 32 + 4);
        short8 f;
        f[0] = f2s(lo.x); f[1] = f2s(lo.y); f[2] = f2s(lo.z); f[3] = f2s(lo.w);
        f[4] = f2s(hi.x); f[5] = f2s(hi.y); f[6] = f2s(hi.z); f[7] = f2s(hi.w);
        bfrag[kc] = f;
    }
    float bias = cb[ocb + n];

    const short* abase = (const short*)xup + ((size_t)(b * HWD) << 8);

#pragma unroll
    for (int mt = 0; mt < 4; mt += 2) {
        f32x4 acc0 = {0.f, 0.f, 0.f, 0.f};
        f32x4 acc1 = {0.f, 0.f, 0.f, 0.f};
        const short8* ar0 = (const short8*)(abase + (((size_t)(hw0 + mt * 16 + n)) << 8) + quad * 8);
        const short8* ar1 = (const short8*)(abase + (((size_t)(hw0 + mt * 16 + 16 + n)) << 8) + quad * 8);
#pragma unroll
        for (int kc = 0; kc < 8; ++kc) {
            short8 a0 = ar0[kc * 4];
            short8 a1 = ar1[kc * 4];
            acc0 = __builtin_amdgcn_mfma_f32_16x16x32_bf16(a0, bfrag[kc], acc0, 0, 0, 0);
            acc1 = __builtin_amdgcn_mfma_f32_16x16x32_bf16(a1, bfrag[kc], acc1, 0, 0, 0);
        }
#pragma unroll
        for (int r = 0; r < 4; ++r) {
            smc[mt * 16 + quad * 4 + r][ocb + n] = acc0[r] + bias;
            smc[mt * 16 + 16 + quad * 4 + r][ocb + n] = acc1[r] + bias;
        }
    }
    __syncthreads();

    const int px = threadIdx.x & 63;
    const int q = threadIdx.x >> 6;
    const int hw = hw0 + px;
    if (q == 0) {
        float a[9];
#pragma unroll
        for (int k = 0; k < 9; ++k) a[k] = fb[k];
        for (int c = 0; c < 64; ++c) {
            float v = smc[px][c];
            const float4* wr = reinterpret_cast<const float4*>(&fwS[c * 12]);
            float4 w0 = wr[0], w1 = wr[1];
            float w8 = fwS[c * 12 + 8];
            a[0] += v * w0.x; a[1] += v * w0.y; a[2] += v * w0.z; a[3] += v * w0.w;
            a[4] += v * w1.x; a[5] += v * w1.y; a[6] += v * w1.z; a[7] += v * w1.w;
            a[8] += v * w8;
        }
        float mx = a[0];
#pragma unroll
        for (int k = 1; k < 9; ++k) mx = fmaxf(mx, a[k]);
        float s = 0.f;
#pragma unroll
        for (int k = 0; k < 9; ++k) { a[k] = expf(a[k] - mx); s += a[k]; }
        float inv = 1.f / s;
        short* kr = (short*)kern + ((size_t)(b * HWD + hw) << 4);
        short8 pk;
#pragma unroll
        for (int k = 0; k < 8; ++k) pk[k] = f2s(a[k] * inv);
        *(short8*)kr = pk;
        kr[8] = f2s(a[8] * inv);
    } else {
        const int oc0 = (q == 3) ? 6 : (q - 1) * 3;
        const int noc = (q == 3) ? 2 : 3;
        float o[3], aa[3];
        for (int i = 0; i < noc; ++i) { o[i] = tb[oc0 + i]; aa[i] = tab[oc0 + i]; }
        for (int c = 0; c < 64; ++c) {
            float v = smc[px][c];
            const float* wr = &swS[c << 4];
#pragma unroll 3
            for (int i = 0; i < noc; ++i) {
                o[i]  += v * wr[2 * (oc0 + i)];
                aa[i] += v * wr[2 * (oc0 + i) + 1];
            }
        }
        for (int i = 0; i < noc; ++i)
            toff[((size_t)(b * 8 + oc0 + i) << 14) + hw] =
                o[i] * (1.f / (1.f + expf(-aa[i])));
    }
}

// ---------------------------------------------------------------------------
// K4b: xfilt_pm[b][hw][c] = sum_k kern[b][hw][k] * xup_pm[b][tap_k(hw)][c]
// ---------------------------------------------------------------------------
__global__ __launch_bounds__(256) void k4b_apply(const bf16* __restrict__ xup,
        const bf16* __restrict__ kern, bf16* __restrict__ xfilt)
{
    int t = blockIdx.x * 256 + threadIdx.x;
    int chunk = t & 31;
    int hw = (t >> 5) & 16383;
    int b = t >> 19;
    int h = hw >> 7, w = hw & 127;

    const short* kr = (const short*)kern + ((size_t)(b * HWD + hw) << 4);
    short8 k8 = *(const short8*)kr;
    float wk[9];
#pragma unroll
    for (int k = 0; k < 8; ++k) wk[k] = s2f(k8[k]);
    wk[8] = s2f(kr[8]);

    float ymask[3] = { h > 0 ? 1.f : 0.f, 1.f, h < 127 ? 1.f : 0.f };
    float xmask[3] = { w > 0 ? 1.f : 0.f, 1.f, w < 127 ? 1.f : 0.f };
    int hy[3] = { (max(h - 1, 0)) << 7, h << 7, (min(h + 1, 127)) << 7 };
    int wx[3] = { max(w - 1, 0), w, min(w + 1, 127) };

    const short* xb = (const short*)xup + ((size_t)(b * HWD) << 8) + chunk * 8;
    float sum[8];
#pragma unroll
    for (int j = 0; j < 8; ++j) sum[j] = 0.f;
#pragma unroll
    for (int dy = 0; dy < 3; ++dy) {
#pragma unroll
        for (int dx = 0; dx < 3; ++dx) {
            float wgt = wk[dy * 3 + dx] * ymask[dy] * xmask[dx];
            short8 v = *(const short8*)(xb + ((size_t)(hy[dy] + wx[dx]) << 8));
#pragma unroll
            for (int j = 0; j < 8; ++j) sum[j] += wgt * s2f(v[j]);
        }
    }
    short8 pk;
#pragma unroll
    for (int j = 0; j < 8; ++j) pk[j] = f2s(sum[j]);
    *(short8*)((short*)xfilt + ((size_t)(b * HWD + hw) << 8) + chunk * 8) = pk;
}

// ---------------------------------------------------------------------------
// K6: trim_op -> out (b,256,16384) fp32
// Phase 1: wave-per-pixel coalesced gather into LDS. Phase 2: transposed
// coalesced stores.
// ---------------------------------------------------------------------------
__global__ __launch_bounds__(256) void k6_trim(const bf16* __restrict__ xfilt,
        const float* __restrict__ toff, float* __restrict__ out)
{
    __shared__ float sm[32][260];
    int b = blockIdx.x >> 9;
    int hw0 = (blockIdx.x & 511) << 5;
    int wave = threadIdx.x >> 6, lane = threadIdx.x & 63;
    int e = lane * 4;
    int g = lane >> 4;
    const short* xb = (const short*)xfilt + ((size_t)(b * HWD) << 8);
    const float* tfx = toff + ((size_t)(b * 8 + 2 * g)     << 14);
    const float* tfy = toff + ((size_t)(b * 8 + 2 * g + 1) << 14);

    for (int i = 0; i < 8; ++i) {
        int pp = wave * 8 + i;
        int hw = hw0 + pp;
        int h = hw >> 7, w = hw & 127;
        float ox = tfx[hw], oy = tfy[hw];
        float ix = fminf(fmaxf(w + ox, 0.f), 127.f);
        float iy = fminf(fmaxf(h + oy, 0.f), 127.f);
        float x0f = floorf(ix), y0f = floorf(iy);
        float fx = ix - x0f, fy = iy - y0f;
        int x0 = (int)x0f, y0 = (int)y0f;
        int x1 = min(x0 + 1, 127), y1 = min(y0 + 1, 127);
        float w00 = (1.f - fx) * (1.f - fy), w01 = fx * (1.f - fy);
        float w10 = (1.f - fx) * fy,        w11 = fx * fy;
        short4v v00 = *(const short4v*)(xb + (((size_t)(y0 << 7) + x0) << 8) + e);
        short4v v01 = *(const short4v*)(xb + (((size_t)(y0 << 7) + x1) << 8) + e);
        short4v v10 = *(const short4v*)(xb + (((size_t)(y1 << 7) + x0) << 8) + e);
        short4v v11 = *(const short4v*)(xb + (((size_t)(y1 << 7) + x1) << 8) + e);
#pragma unroll
        for (int j = 0; j < 4; ++j) {
            sm[pp][e + j] = w00 * s2f(v00[j]) + w01 * s2f(v01[j])
                          + w10 * s2f(v10[j]) + w11 * s2f(v11[j]);
        }
    }
    __syncthreads();
    int lp = threadIdx.x & 31;
    int c0 = (threadIdx.x >> 5) << 5;
    float* ob = out + (((size_t)b << 8) << 14) + hw0 + lp;
#pragma unroll 8
    for (int k = 0; k < 32; ++k) {
        int c = c0 + k;
        ob[(size_t)c << 14] = sm[lp][c];
    }
}

extern "C" void kernel_launch(void* const* d_in, const int* in_sizes, int n_in,
                              void* d_out, int out_size, void* d_ws, size_t ws_size,
                              hipStream_t stream)
{
    const float* x       = (const float*)d_in[0];
    const float* w_off   = (const float*)d_in[1];
    const float* b_off   = (const float*)d_in[2];
    const float* w_ast   = (const float*)d_in[3];
    const float* b_ast   = (const float*)d_in[4];
    const float* comp_w  = (const float*)d_in[5];
    const float* comp_b  = (const float*)d_in[6];
    const float* filt_w  = (const float*)d_in[7];
    const float* filt_b  = (const float*)d_in[8];
    const float* trim_w  = (const float*)d_in[9];
    const float* trim_b  = (const float*)d_in[10];
    const float* trim_aw = (const float*)d_in[11];
    const float* trim_ab = (const float*)d_in[12];
    float* out = (float*)d_out;

    char* ws = (char*)d_ws;
    float* offpm = (float*)(ws);                 // 2 MiB (b,4096,32) — dead after k2
    bf16*  kern  = (bf16*) (ws);                 // 2 MiB, reuses off region (k3+)
    bf16*  xup   = (bf16*) (ws + (2ull << 20));  // 32 MiB pixel-major (b,hw,256)
    bf16*  xpm   = (bf16*) (ws + (34ull << 20)); // 8 MiB pixel-major (b,4096,256)
    bf16*  xfilt = (bf16*) (ws + (50ull << 20)); // 32 MiB pixel-major (b,hw,256)
    float* toff  = (float*)(ws + (82ull << 20)); // 2 MiB (b,8,16384)

    hipLaunchKernelGGL(k0_xpose,    dim3(256),   dim3(256), 0, stream,
                       x, xpm);
    hipLaunchKernelGGL(k1_off,      dim3(256),   dim3(256), 0, stream,
                       xpm, w_off, b_off, w_ast, b_ast, offpm);
    hipLaunchKernelGGL(k2_defsample,dim3(16384), dim3(256), 0, stream,
                       xpm, offpm, xup);
    hipLaunchKernelGGL(k3_fused,    dim3(1024),  dim3(256), 0, stream,
                       xup, comp_w, comp_b, filt_w, filt_b,
                       trim_w, trim_b, trim_aw, trim_ab, kern, toff);
    hipLaunchKernelGGL(k4b_apply,   dim3(8192),  dim3(256), 0, stream,
                       xup, kern, xfilt);
    hipLaunchKernelGGL(k6_trim,     dim3(2048),  dim3(256), 0, stream,
                       xfilt, toff, out);
}